// Round 12
// baseline (657.776 us; speedup 1.0000x reference)
//
#include <hip/hip_runtime.h>

typedef __attribute__((ext_vector_type(8))) short short8;
typedef __attribute__((ext_vector_type(4))) float f32x4;
union frag_u { short8 v; unsigned short u[8]; };

__device__ __forceinline__ float bf2f(unsigned short b) {
  unsigned int u = ((unsigned int)b) << 16;
  float f; __builtin_memcpy(&f, &u, 4); return f;
}
__device__ __forceinline__ unsigned short f2bf(float f) {
  unsigned int u; __builtin_memcpy(&u, &f, 4);
  return (unsigned short)((u + 0x7FFFu + ((u >> 16) & 1u)) >> 16);
}
__device__ __forceinline__ unsigned short hi_of(float f) { return f2bf(f); }
__device__ __forceinline__ unsigned short lo_of(float f) {
  unsigned short h = f2bf(f); return f2bf(f - bf2f(h));
}
__device__ __forceinline__ float sigm(float x) {
  return __builtin_amdgcn_rcpf(1.f + __expf(-x));
}
__device__ __forceinline__ float tanh_(float x) {
  return 1.f - 2.f * __builtin_amdgcn_rcpf(1.f + __expf(2.f * x));
}

// Fallback dtype detector. flag: 0 = bf16, 1 = f32.
__global__ void detect_dtype_kernel(const unsigned short* s, int* flag) {
  int i = threadIdx.x;   // 64 threads
  unsigned short v = s[2 * i];
  int e = (v >> 7) & 0xFF;
  unsigned long long m = __ballot(e < 100 || e > 140);
  if (i == 0) *flag = (__popcll(m) >= 16) ? 1 : 0;
}

// ============ single-wave kernel: 16 rows, whole network, ZERO barriers ====
// 64 threads = 1 wave per block, grid = 512 (8192 rows / 16). The wave owns
// all 13 gate-permuted LSTM tiles (weights persistent in 312/208 VGPRs,
// __launch_bounds__(64,1) allows the full 512-VGPR budget), its 16 rows'
// state, and the tail MLP. Per step: 6 (KC) ds_read_b128 A-frags read ONCE
// (vs 13x redundantly before), 78 MFMAs, park in private sG, wave-local gate
// readback (LDS ops of one wave are in-order -> no barrier, R6-proven),
// in-register activation of 12.5 items/lane, h/x writes to double-buffered
// sA. x(t+1) global loads issued at the top of step t (T14 issue-early).
template <bool F32>
__global__ __launch_bounds__(64, 1) void value_net_kernel(
    const void* state_, const void* wih_, const void* whh_,
    const void* bih_, const void* bhh_,
    const void* w1_, const void* b1_, const void* w2_, const void* b2_,
    const void* w3_, const void* b3_, const void* w4_, const void* b4_,
    void* out_, const int* flag)
{
  if (flag && *flag != (F32 ? 1 : 0)) return;

  // A column layout, LSTM phase (R6-proven):
  //  bf16: [x(0..6) | h_hi(7..56) | h_lo(57..106) | 0-pad..127]           K=4x32
  //  f32 : [x_hi(0..6) | x_lo(7..13) | x_hi(14..20) | h_hi(21..70) |
  //         h_lo(71..120) | h_hi(121..170) | 0-pad..191]                  K=6x32
  constexpr int AS = F32 ? 328 : 168;
  constexpr int KC = F32 ? 6 : 4;

  __shared__ __align__(16) unsigned short sA[2][16 * AS];  // double-buffered
  __shared__ __align__(16) float sG[208 * 20];             // park + tail G

  const unsigned short* st16 = (const unsigned short*)state_;
  const float*          stf  = (const float*)state_;

  const int lane = threadIdx.x;        // 0..63
  const int col  = lane & 15;
  const int quad = lane >> 4;
  const int r0   = blockIdx.x * 16;

  // ---- zero BOTH sA buffers ----
  {
    unsigned int* a32 = (unsigned int*)&sA[0][0];
    for (int idx = lane; idx < 16 * AS; idx += 64) a32[idx] = 0;
  }

  // ---- LSTM weight getter (n is ORIGINAL column index) ----
  auto W_lstm = [&](int k, int n) -> unsigned short {
    if constexpr (!F32) {
      const unsigned short* wih = (const unsigned short*)wih_;
      const unsigned short* whh = (const unsigned short*)whh_;
      if (k < 7)   return wih[k * 200 + n];
      if (k < 57)  return whh[(k - 7) * 200 + n];
      if (k < 107) return whh[(k - 57) * 200 + n];
      return (unsigned short)0;
    } else {
      const float* wih = (const float*)wih_;
      const float* whh = (const float*)whh_;
      if (k < 7)   return hi_of(wih[k * 200 + n]);
      if (k < 14)  return hi_of(wih[(k - 7) * 200 + n]);
      if (k < 21)  return lo_of(wih[(k - 14) * 200 + n]);
      if (k < 71)  return hi_of(whh[(k - 21) * 200 + n]);
      if (k < 121) return hi_of(whh[(k - 71) * 200 + n]);
      if (k < 171) return lo_of(whh[(k - 121) * 200 + n]);
      return (unsigned short)0;
    }
  };
  auto ldf = [&](const void* p, int i) -> float {
    if constexpr (F32) return ((const float*)p)[i];
    else               return bf2f(((const unsigned short*)p)[i]);
  };

  // ---- persistent gate-permuted weight fragments: ALL 13 tiles ----
  frag_u wf[13][KC];
  float  wb[13];
  #pragma unroll
  for (int T = 0; T < 13; ++T) {
    int nn = T * 16 + col;                                 // permuted col
    int no = (nn < 200) ? ((nn & 3) * 50 + (nn >> 2)) : 0; // original col
    #pragma unroll
    for (int kc = 0; kc < KC; ++kc)
      #pragma unroll
      for (int j = 0; j < 8; ++j) {
        int k = kc * 32 + quad * 8 + j;
        wf[T][kc].u[j] = (nn < 200) ? W_lstm(k, no) : (unsigned short)0;
      }
    wb[T] = (nn < 200) ? (ldf(bih_, no) + ldf(bhh_, no)) : 0.f;
  }

  float c_[13], hf[13];
  #pragma unroll
  for (int T = 0; T < 13; ++T) { c_[T] = 0.f; hf[T] = 0.f; }

  // ---- x lane mapping: i0 = lane (rows 0..9), i1 = lane+64 (rows 9..15) ----
  const int i1 = lane + 64;
  const bool v1 = i1 < 112;
  const int xm0 = lane / 7, xd0 = lane - (lane / 7) * 7;
  const int xm1 = i1 / 7,   xd1 = i1 - (i1 / 7) * 7;
  auto xg = [&](int t, int xm, int xd) -> size_t {
    return (size_t)(r0 + xm) * 832 + (size_t)t * 13 + 6 + xd;
  };
  auto xput = [&](unsigned short* sAw, int xm, int xd, float fv, unsigned short bv) {
    if constexpr (!F32) { sAw[xm * AS + xd] = bv; }
    else {
      unsigned short h = f2bf(fv);
      sAw[xm * AS + xd] = h; sAw[xm * AS + 14 + xd] = h;
      sAw[xm * AS + 7 + xd] = f2bf(fv - bf2f(h));
    }
  };

  // x(0) into buf0
  if constexpr (!F32) {
    xput(&sA[0][0], xm0, xd0, 0.f, st16[xg(0, xm0, xd0)]);
    if (v1) xput(&sA[0][0], xm1, xd1, 0.f, st16[xg(0, xm1, xd1)]);
  } else {
    xput(&sA[0][0], xm0, xd0, stf[xg(0, xm0, xd0)], 0);
    if (v1) xput(&sA[0][0], xm1, xd1, stf[xg(0, xm1, xd1)], 0);
  }

  // ---- LSTM: 64 steps, no barriers (wave-local LDS ordering) ----
  for (int t = 0; t < 64; ++t) {
    const unsigned short* sAr = &sA[t & 1][0];
    unsigned short*       sAw = &sA[(t & 1) ^ 1][0];

    // issue x(t+1) loads early; consumed at end of this step
    unsigned short xb0 = 0, xb1 = 0; float xf0 = 0.f, xf1 = 0.f;
    if (t < 63) {
      if constexpr (!F32) {
        xb0 = st16[xg(t + 1, xm0, xd0)];
        if (v1) xb1 = st16[xg(t + 1, xm1, xd1)];
      } else {
        xf0 = stf[xg(t + 1, xm0, xd0)];
        if (v1) xf1 = stf[xg(t + 1, xm1, xd1)];
      }
    }

    // A-fragments read ONCE for all 13 tiles
    short8 a[KC];
    #pragma unroll
    for (int kc = 0; kc < KC; ++kc)
      a[kc] = *(const short8*)&sAr[col * AS + kc * 32 + quad * 8];

    // 13 gate-tiles, park each in the private sG strip
    #pragma unroll
    for (int T = 0; T < 13; ++T) {
      f32x4 acc = {wb[T], wb[T], wb[T], wb[T]};
      #pragma unroll
      for (int kc = 0; kc < KC; ++kc)
        acc = __builtin_amdgcn_mfma_f32_16x16x32_bf16(a[kc], wf[T][kc].v, acc, 0, 0, 0);
      *(f32x4*)&sG[(T * 16 + col) * 20 + quad * 4] = acc;
    }

    // wave-local readback + activation: item (m=col, u=4T+quad)
    #pragma unroll
    for (int T = 0; T < 13; ++T) {
      if (T < 12 || quad < 2) {          // u = 4T+quad < 50
        int u  = 4 * T + quad;
        int nb = T * 16 + quad * 4;
        float gi = sG[(nb + 0) * 20 + col];
        float gf = sG[(nb + 1) * 20 + col];
        float gg = sG[(nb + 2) * 20 + col];
        float go = sG[(nb + 3) * 20 + col];
        float cc = sigm(gf) * c_[T] + sigm(gi) * tanh_(gg);
        c_[T] = cc;
        float h = sigm(go) * tanh_(cc);
        if (t < 63) {
          unsigned short hb = f2bf(h);
          unsigned short hl = f2bf(h - bf2f(hb));
          if constexpr (!F32) {
            sAw[col * AS + 7 + u] = hb; sAw[col * AS + 57 + u] = hl;
          } else {
            sAw[col * AS + 21 + u] = hb; sAw[col * AS + 121 + u] = hb;
            sAw[col * AS + 71 + u] = hl;
          }
        } else hf[T] = h;
      }
    }

    if (t < 63) {
      if constexpr (!F32) {
        xput(sAw, xm0, xd0, 0.f, xb0);
        if (v1) xput(sAw, xm1, xd1, 0.f, xb1);
      } else {
        xput(sAw, xm0, xd0, xf0, 0);
        if (v1) xput(sAw, xm1, xd1, xf1, 0);
      }
    }
  }

  // ---- tail MLP, same wave (solo) ----
  // joint: bf16 [self(0..5)|h_hi(6..55)|h_lo(56..105)] K=106->128
  //        f32  [self_hi(0..5)|h_hi(6..55)|self_lo(56..61)|h_lo(62..111)] K=112->128
  unsigned short* sA0 = &sA[0][0];
  {
    constexpr int Z0 = F32 ? 112 : 104;
    constexpr int Z1 = F32 ? 192 : 128;
    for (int idx = lane; idx < 16 * (Z1 - Z0); idx += 64) {
      int m = idx & 15, n2 = Z0 + (idx >> 4);
      sA0[m * AS + n2] = 0;
    }
  }
  #pragma unroll
  for (int T = 0; T < 13; ++T) {
    if (T < 12 || quad < 2) {
      int u = 4 * T + quad;
      unsigned short hb = f2bf(hf[T]);
      unsigned short hl = f2bf(hf[T] - bf2f(hb));
      sA0[col * AS + 6 + u] = hb;
      if constexpr (!F32) sA0[col * AS + 56 + u] = hl;
      else                sA0[col * AS + 62 + u] = hl;
    }
  }
  for (int idx = lane; idx < 96; idx += 64) {
    int m = idx / 6, d = idx - (idx / 6) * 6;
    if constexpr (!F32) sA0[m * AS + d] = st16[(size_t)(r0 + m) * 832 + d];
    else {
      float f = stf[(size_t)(r0 + m) * 832 + d];
      sA0[m * AS + d] = hi_of(f); sA0[m * AS + 56 + d] = lo_of(f);
    }
  }

  // solo mfma layer: sA0 @ W -> sG
  auto layer = [&](int kc_n, int ntiles, int N, auto getb, auto getw) {
    for (int tile = 0; tile < ntiles; ++tile) {
      int nn = tile * 16 + col;
      float b = (nn < N) ? getb(nn) : 0.f;
      f32x4 acc = {b, b, b, b};
      for (int kc = 0; kc < kc_n; ++kc) {
        short8 a = *(const short8*)&sA0[col * AS + kc * 32 + quad * 8];
        frag_u w;
        #pragma unroll
        for (int j = 0; j < 8; ++j) {
          int k = kc * 32 + quad * 8 + j;
          w.u[j] = (nn < N) ? getw(k, nn) : (unsigned short)0;
        }
        acc = __builtin_amdgcn_mfma_f32_16x16x32_bf16(a, w.v, acc, 0, 0, 0);
      }
      *(f32x4*)&sG[nn * 20 + quad * 4] = acc;
    }
  };
  auto refill = [&](int N, int loOff, int Kpad) {
    for (int idx = lane; idx < 16 * Kpad; idx += 64) {
      int m = idx & 15, nn = idx >> 4;
      unsigned short v = 0;
      if (nn < N) v = f2bf(fmaxf(sG[nn * 20 + m], 0.f));
      else if (nn >= loOff && nn < loOff + N)
        v = lo_of(fmaxf(sG[(nn - loOff) * 20 + m], 0.f));
      sA0[m * AS + nn] = v;
    }
  };

  // L1: -> 150
  layer(4, 10, 150,
    [&](int nn) { return ldf(b1_, nn); },
    [&](int k, int nn) -> unsigned short {
      if constexpr (!F32) {
        const unsigned short* w1 = (const unsigned short*)w1_;
        if (k < 56)  return w1[k * 150 + nn];
        if (k < 106) return w1[(k - 50) * 150 + nn];
        return (unsigned short)0;
      } else {
        const float* w1 = (const float*)w1_;
        if (k < 56)  return hi_of(w1[k * 150 + nn]);
        if (k < 112) return hi_of(w1[(k - 56) * 150 + nn]);
        return (unsigned short)0;
      }
    });
  if constexpr (!F32) refill(150, 160, 160); else refill(150, 150, 320);

  // L2: 150 -> 100
  layer(F32 ? 10 : 5, 7, 100,
    [&](int nn) { return ldf(b2_, nn); },
    [&](int k, int nn) -> unsigned short {
      if constexpr (!F32) {
        const unsigned short* w2 = (const unsigned short*)w2_;
        return (k < 150) ? w2[k * 100 + nn] : (unsigned short)0;
      } else {
        const float* w2 = (const float*)w2_;
        if (k < 150) return hi_of(w2[k * 100 + nn]);
        if (k < 300) return hi_of(w2[(k - 150) * 100 + nn]);
        return (unsigned short)0;
      }
    });
  if constexpr (!F32) refill(100, 128, 128); else refill(100, 100, 224);

  // L3: 100 -> 100
  layer(F32 ? 7 : 4, 7, 100,
    [&](int nn) { return ldf(b3_, nn); },
    [&](int k, int nn) -> unsigned short {
      if constexpr (!F32) {
        const unsigned short* w3 = (const unsigned short*)w3_;
        return (k < 100) ? w3[k * 100 + nn] : (unsigned short)0;
      } else {
        const float* w3 = (const float*)w3_;
        if (k < 100) return hi_of(w3[k * 100 + nn]);
        if (k < 200) return hi_of(w3[(k - 100) * 100 + nn]);
        return (unsigned short)0;
      }
    });

  // L4: relu(sG) @ w4 + b4, 4-way k-split + cross-quad shuffle reduce
  {
    float s = 0.f;
    for (int j = quad; j < 100; j += 4)
      s += fmaxf(sG[j * 20 + col], 0.f) * ldf(w4_, j);
    s += __shfl_xor(s, 16);
    s += __shfl_xor(s, 32);
    if (quad == 0) {
      float v = s + ldf(b4_, 0);
      if constexpr (!F32) ((unsigned short*)out_)[r0 + col] = f2bf(v);
      else                ((float*)out_)[r0 + col] = v;
    }
  }
}

extern "C" void kernel_launch(void* const* d_in, const int* in_sizes, int n_in,
                              void* d_out, int out_size, void* d_ws, size_t ws_size,
                              hipStream_t stream) {
  (void)n_in; (void)out_size;
  // d_in[1..10] (mlp1_* / attn_*) are dead code in the reference — unused.
  const void* state = d_in[0];
  const void* wih = d_in[11]; const void* whh = d_in[12];
  const void* bih = d_in[13]; const void* bhh = d_in[14];
  const void* w1  = d_in[15]; const void* b1  = d_in[16];
  const void* w2  = d_in[17]; const void* b2  = d_in[18];
  const void* w3  = d_in[19]; const void* b3  = d_in[20];
  const void* w4  = d_in[21]; const void* b4  = d_in[22];

  const long long F32B  = 8192LL * 64 * 13 * 4;
  const long long BF16B = 8192LL * 64 * 13 * 2;
  long long sz = in_sizes ? (long long)in_sizes[0] : -1;

  if (sz == F32B) {
    value_net_kernel<true><<<dim3(512), dim3(64), 0, stream>>>(
        state, wih, whh, bih, bhh, w1, b1, w2, b2, w3, b3, w4, b4, d_out,
        (const int*)nullptr);
  } else if (sz == BF16B) {
    value_net_kernel<false><<<dim3(512), dim3(64), 0, stream>>>(
        state, wih, whh, bih, bhh, w1, b1, w2, b2, w3, b3, w4, b4, d_out,
        (const int*)nullptr);
  } else if (ws_size >= sizeof(int)) {
    int* flag = (int*)d_ws;
    detect_dtype_kernel<<<dim3(1), dim3(64), 0, stream>>>(
        (const unsigned short*)state, flag);
    value_net_kernel<false><<<dim3(512), dim3(64), 0, stream>>>(
        state, wih, whh, bih, bhh, w1, b1, w2, b2, w3, b3, w4, b4, d_out, flag);
    value_net_kernel<true><<<dim3(512), dim3(64), 0, stream>>>(
        state, wih, whh, bih, bhh, w1, b1, w2, b2, w3, b3, w4, b4, d_out, flag);
  } else {
    value_net_kernel<false><<<dim3(512), dim3(64), 0, stream>>>(
        state, wih, whh, bih, bhh, w1, b1, w2, b2, w3, b3, w4, b4, d_out,
        (const int*)nullptr);
  }
}

// Round 13
// 232.831 us; speedup vs baseline: 2.8251x; 2.8251x over previous
//
#include <hip/hip_runtime.h>

typedef __attribute__((ext_vector_type(8))) short short8;
typedef __attribute__((ext_vector_type(4))) float f32x4;
union frag_u { short8 v; unsigned short u[8]; };

__device__ __forceinline__ float bf2f(unsigned short b) {
  unsigned int u = ((unsigned int)b) << 16;
  float f; __builtin_memcpy(&f, &u, 4); return f;
}
__device__ __forceinline__ unsigned short f2bf(float f) {
  unsigned int u; __builtin_memcpy(&u, &f, 4);
  return (unsigned short)((u + 0x7FFFu + ((u >> 16) & 1u)) >> 16);
}
__device__ __forceinline__ unsigned short hi_of(float f) { return f2bf(f); }
__device__ __forceinline__ unsigned short lo_of(float f) {
  unsigned short h = f2bf(f); return f2bf(f - bf2f(h));
}
__device__ __forceinline__ float sigm(float x) {
  return __builtin_amdgcn_rcpf(1.f + __expf(-x));
}
__device__ __forceinline__ float tanh_(float x) {
  return 1.f - 2.f * __builtin_amdgcn_rcpf(1.f + __expf(2.f * x));
}

// Fallback dtype detector (parallel). flag: 0 = bf16, 1 = f32.
__global__ void detect_dtype_kernel(const unsigned short* s, int* flag) {
  int i = threadIdx.x;   // 64 threads
  unsigned short v = s[2 * i];
  int e = (v >> 7) & 0xFF;
  unsigned long long m = __ballot(e < 100 || e > 140);
  if (i == 0) *flag = (__popcll(m) >= 16) ? 1 : 0;
}

// sA(16 x Kpad bf16, stride AS) @ W(K x N) -> sG[n][m]  (G stride 20)
// A-frag: lane holds A[m=lane&15][k=kc*32+quad*8+j]; B-frag: W[k][n=tile*16+(lane&15)]
// C/D: row m = quad*4+reg, col n = lane&15   [verified m89/m91]
template <int AS, typename GetB, typename GetW>
__device__ __forceinline__ void mfma_layer(const unsigned short* sA, float* sG,
    int wave, int col, int quad, int kc_n, int ntiles, int N, GetB getb, GetW getw)
{
  for (int tile = wave; tile < ntiles; tile += 16) {
    int n = tile * 16 + col;
    float b = (n < N) ? getb(n) : 0.f;
    f32x4 acc = {b, b, b, b};
    for (int kc = 0; kc < kc_n; ++kc) {
      short8 a = *(const short8*)&sA[col * AS + kc * 32 + quad * 8];
      frag_u w;
      #pragma unroll
      for (int j = 0; j < 8; ++j) {
        int k = kc * 32 + quad * 8 + j;
        w.u[j] = (n < N) ? getw(k, n) : (unsigned short)0;
      }
      acc = __builtin_amdgcn_mfma_f32_16x16x32_bf16(a, w.v, acc, 0, 0, 0);
    }
    *(f32x4*)&sG[n * 20 + quad * 4] = acc;
  }
}

// relu(sG col) -> sA as bf16 hi at [0,N), optional lo at [loOff,loOff+N), zero pad to Kpad
template <int AS, bool LO>
__device__ __forceinline__ void relu_fill(const float* sG, unsigned short* sA,
                                          int tid, int N, int loOff, int Kpad) {
  for (int idx = tid; idx < 16 * Kpad; idx += 1024) {
    int m = idx & 15, n = idx >> 4;
    unsigned short v = 0;
    if (n < N) {
      v = f2bf(fmaxf(sG[n * 20 + m], 0.f));
    } else if (LO && n >= loOff && n < loOff + N) {
      float x = fmaxf(sG[(n - loOff) * 20 + m], 0.f);
      v = lo_of(x);
    }
    sA[m * AS + n] = v;
  }
}

// 1024 threads / 16 waves, 16 rows per block, grid = 512.
// SINGLE-PHASE LSTM (best-measured config across 12 rounds, hot ~141-145 us):
// weight columns gate-permuted (n_new = u*4+gate). Wave w's MFMA tile holds
// all 4 gates for its 4 u-values x 16 rows. The wave parks acc in its
// PRIVATE sG strip and reads back its own item's 4 gates wave-locally
// (no barrier), runs the activation, writes h to the double-buffered sA.
// ONE barrier per step. Waves 13..15 feed x (register-prefetched global).
template <bool F32>
__global__ __launch_bounds__(1024, 8) void value_net_kernel(
    const void* state_, const void* wih_, const void* whh_,
    const void* bih_, const void* bhh_,
    const void* w1_, const void* b1_, const void* w2_, const void* b2_,
    const void* w3_, const void* b3_, const void* w4_, const void* b4_,
    void* out_, const int* flag)
{
  if (flag && *flag != (F32 ? 1 : 0)) return;   // fallback path: other variant runs

  // A column layout, LSTM phase:
  //  bf16: [x(0..6) | h_hi(7..56) | h_lo(57..106) | 0-pad..127]           K=4x32
  //  f32 : [x_hi(0..6) | x_lo(7..13) | x_hi(14..20) | h_hi(21..70) |
  //         h_lo(71..120) | h_hi(121..170) | 0-pad..191]                  K=6x32
  //        paired with W rows [Wx_hi|Wx_hi|Wx_lo|Wh_hi|Wh_hi|Wh_lo] (tri-product)
  constexpr int AS = F32 ? 328 : 168;   // max Kpad (+8 pad)
  constexpr int KC = F32 ? 6 : 4;

  __shared__ __align__(16) unsigned short sA[2][16 * AS];  // double-buffered
  __shared__ __align__(16) float sG[208 * 20];             // LSTM park + tail MLP

  const unsigned short* st16 = (const unsigned short*)state_;
  const float*          stf  = (const float*)state_;

  const int tid  = threadIdx.x;
  const int wave = tid >> 6;            // 0..15
  const int lane = tid & 63;
  const int col  = lane & 15;
  const int quad = lane >> 4;
  const int r0   = blockIdx.x * 16;

  // ---- zero BOTH sA buffers (h0 = 0 and all K padding) ----
  {
    unsigned int* a32 = (unsigned int*)&sA[0][0];
    constexpr int ZT = 16 * AS;        // uints across both buffers
    #pragma unroll
    for (int i = 0; i < (ZT + 1023) / 1024; ++i) {
      int idx = tid + i * 1024;
      if (idx < ZT) a32[idx] = 0;
    }
  }

  // ---- LSTM weight getter (n is ORIGINAL column index) ----
  auto W_lstm = [&](int k, int n) -> unsigned short {
    if constexpr (!F32) {
      const unsigned short* wih = (const unsigned short*)wih_;
      const unsigned short* whh = (const unsigned short*)whh_;
      if (k < 7)   return wih[k * 200 + n];
      if (k < 57)  return whh[(k - 7) * 200 + n];
      if (k < 107) return whh[(k - 57) * 200 + n];
      return (unsigned short)0;
    } else {
      const float* wih = (const float*)wih_;
      const float* whh = (const float*)whh_;
      if (k < 7)   return hi_of(wih[k * 200 + n]);
      if (k < 14)  return hi_of(wih[(k - 7) * 200 + n]);
      if (k < 21)  return lo_of(wih[(k - 14) * 200 + n]);
      if (k < 71)  return hi_of(whh[(k - 21) * 200 + n]);
      if (k < 121) return hi_of(whh[(k - 71) * 200 + n]);
      if (k < 171) return lo_of(whh[(k - 121) * 200 + n]);
      return (unsigned short)0;
    }
  };
  auto ldf = [&](const void* p, int i) -> float {
    if constexpr (F32) return ((const float*)p)[i];
    else               return bf2f(((const unsigned short*)p)[i]);
  };

  // ---- persistent LSTM weight fragments: 13 gate-permuted N-tiles ----
  const bool hasTile = (wave < 13);
  frag_u wf[KC];
  float  wb = 0.f;
  if (hasTile) {
    int nn = wave * 16 + col;                              // permuted col
    int no = (nn < 200) ? ((nn & 3) * 50 + (nn >> 2)) : 0; // original col
    #pragma unroll
    for (int kc = 0; kc < KC; ++kc) {
      #pragma unroll
      for (int j = 0; j < 8; ++j) {
        int k = kc * 32 + quad * 8 + j;
        wf[kc].u[j] = (nn < 200) ? W_lstm(k, no) : (unsigned short)0;
      }
    }
    wb = (nn < 200) ? (ldf(bih_, no) + ldf(bhh_, no)) : 0.f;
  }

  // per-lane LSTM item: (m = col, u = wave*4 + quad)
  const int  u_   = wave * 4 + quad;
  const bool iact = hasTile && (u_ < 50);
  float c_ = 0.f, hf = 0.f;

  // ---- x-feed: waves 13..15, threads 832..943 (16 rows x 7 dims) ----
  const bool isx = (tid >= 832) && (tid < 944);
  const int  xm = (tid - 832) / 7, xd = (tid - 832) - ((tid - 832) / 7) * 7;
  auto xgidx = [&](int t) -> size_t { return (size_t)(r0 + xm) * 832 + t * 13 + 6 + xd; };
  auto xwrite = [&](unsigned short* sAw, float fv, unsigned short bv) {
    if constexpr (!F32) { sAw[xm * AS + xd] = bv; }
    else {
      unsigned short h = f2bf(fv);
      sAw[xm * AS + xd] = h; sAw[xm * AS + 14 + xd] = h;
      sAw[xm * AS + 7 + xd] = f2bf(fv - bf2f(h));
    }
  };
  unsigned short xv16 = 0; float xvf = 0.f;   // prefetched x_{t+1}

  __syncthreads();
  if (isx) {   // x_0 into buf0 + prefetch x_1
    if constexpr (!F32) { xwrite(&sA[0][0], 0.f, st16[xgidx(0)]); xv16 = st16[xgidx(1)]; }
    else                { xwrite(&sA[0][0], stf[xgidx(0)], 0);    xvf  = stf[xgidx(1)]; }
  }
  __syncthreads();

  // ---- LSTM: 64 steps, ONE barrier per step ----
  for (int t = 0; t < 64; ++t) {
    const unsigned short* sAr = &sA[t & 1][0];
    unsigned short*       sAw = &sA[(t & 1) ^ 1][0];

    if (hasTile) {
      short8 a[KC];
      #pragma unroll
      for (int kc = 0; kc < KC; ++kc)
        a[kc] = *(const short8*)&sAr[col * AS + kc * 32 + quad * 8];
      f32x4 acc = {wb, wb, wb, wb};
      #pragma unroll
      for (int kc = 0; kc < KC; ++kc)
        acc = __builtin_amdgcn_mfma_f32_16x16x32_bf16(a[kc], wf[kc].v, acc, 0, 0, 0);
      // park tile in this wave's private sG strip (n_new = wave*16+col)
      *(f32x4*)&sG[(wave * 16 + col) * 20 + quad * 4] = acc;

      if (iact) {
        // wave-local readback: item (m=col, u=u_) gates at n_new = u_*4+g
        int nb = (wave * 16 + quad * 4);
        float gi = sG[(nb + 0) * 20 + col];
        float gf = sG[(nb + 1) * 20 + col];
        float gg = sG[(nb + 2) * 20 + col];
        float go = sG[(nb + 3) * 20 + col];
        float cc = sigm(gf) * c_ + sigm(gi) * tanh_(gg);
        c_ = cc;
        float h = sigm(go) * tanh_(cc);
        if (t < 63) {
          unsigned short hb = f2bf(h);
          unsigned short hl = f2bf(h - bf2f(hb));
          if constexpr (!F32) {
            sAw[col * AS + 7 + u_] = hb; sAw[col * AS + 57 + u_] = hl;
          } else {
            sAw[col * AS + 21 + u_] = hb; sAw[col * AS + 121 + u_] = hb;
            sAw[col * AS + 71 + u_] = hl;
          }
        } else hf = h;
      }
    } else if (isx && t < 63) {
      if constexpr (!F32) xwrite(sAw, 0.f, xv16); else xwrite(sAw, xvf, 0);
      if (t < 62) { if constexpr (!F32) xv16 = st16[xgidx(t + 2)]; else xvf = stf[xgidx(t + 2)]; }
    }
    __syncthreads();
  }

  // ---- tail MLP, fused (uses sA[0]) ----
  // joint cols: bf16 [self(0..5)|h_hi(6..55)|h_lo(56..105)] K=106->128
  //             f32  [self_hi(0..5)|h_hi(6..55)|self_lo(56..61)|h_lo(62..111)] K=112->128
  unsigned short* sA0 = &sA[0][0];
  // Selective zero: only the stale pad columns need clearing — the joint
  // fill overwrites [0,106) bf16 / [0,112) f32, and the LSTM left stale h
  // in the region beyond. bf16: clear [104,128); f32: clear [112,192).
  {
    constexpr int Z0 = F32 ? 112 : 104;
    constexpr int Z1 = F32 ? 192 : 128;
    for (int idx = tid; idx < 16 * (Z1 - Z0); idx += 1024) {
      int m = idx & 15, n = Z0 + (idx >> 4);
      sA0[m * AS + n] = 0;
    }
  }
  __syncthreads();
  if (iact) {
    unsigned short hb = f2bf(hf);
    unsigned short hl = f2bf(hf - bf2f(hb));
    sA0[col * AS + 6 + u_] = hb;
    if constexpr (!F32) sA0[col * AS + 56 + u_] = hl; else sA0[col * AS + 62 + u_] = hl;
  }
  if (tid < 96) {
    int m = tid / 6, d = tid - (tid / 6) * 6;
    if constexpr (!F32) sA0[m * AS + d] = st16[(size_t)(r0 + m) * 832 + d];
    else {
      float f = stf[(size_t)(r0 + m) * 832 + d];
      sA0[m * AS + d] = hi_of(f); sA0[m * AS + 56 + d] = lo_of(f);
    }
  }
  __syncthreads();

  // L1: -> 150
  mfma_layer<AS>(sA0, sG, wave, col, quad, 4, 10, 150,
    [&](int n) { return ldf(b1_, n); },
    [&](int k, int n) -> unsigned short {
      if constexpr (!F32) {
        const unsigned short* w1 = (const unsigned short*)w1_;
        if (k < 56)  return w1[k * 150 + n];
        if (k < 106) return w1[(k - 50) * 150 + n];
        return (unsigned short)0;
      } else {
        const float* w1 = (const float*)w1_;
        if (k < 56)  return hi_of(w1[k * 150 + n]);
        if (k < 112) return hi_of(w1[(k - 56) * 150 + n]);
        return (unsigned short)0;
      }
    });
  __syncthreads();
  if constexpr (!F32) relu_fill<AS, false>(sG, sA0, tid, 150, 160, 160);
  else                relu_fill<AS, true >(sG, sA0, tid, 150, 150, 320);
  __syncthreads();

  // L2: 150 -> 100
  mfma_layer<AS>(sA0, sG, wave, col, quad, F32 ? 10 : 5, 7, 100,
    [&](int n) { return ldf(b2_, n); },
    [&](int k, int n) -> unsigned short {
      if constexpr (!F32) {
        const unsigned short* w2 = (const unsigned short*)w2_;
        return (k < 150) ? w2[k * 100 + n] : (unsigned short)0;
      } else {
        const float* w2 = (const float*)w2_;
        if (k < 150) return hi_of(w2[k * 100 + n]);
        if (k < 300) return hi_of(w2[(k - 150) * 100 + n]);
        return (unsigned short)0;
      }
    });
  __syncthreads();
  if constexpr (!F32) relu_fill<AS, false>(sG, sA0, tid, 100, 128, 128);
  else                relu_fill<AS, true >(sG, sA0, tid, 100, 100, 224);
  __syncthreads();

  // L3: 100 -> 100
  mfma_layer<AS>(sA0, sG, wave, col, quad, F32 ? 7 : 4, 7, 100,
    [&](int n) { return ldf(b3_, n); },
    [&](int k, int n) -> unsigned short {
      if constexpr (!F32) {
        const unsigned short* w3 = (const unsigned short*)w3_;
        return (k < 100) ? w3[k * 100 + n] : (unsigned short)0;
      } else {
        const float* w3 = (const float*)w3_;
        if (k < 100) return hi_of(w3[k * 100 + n]);
        if (k < 200) return hi_of(w3[(k - 100) * 100 + n]);
        return (unsigned short)0;
      }
    });
  __syncthreads();

  // L4: relu(sG) @ w4 + b4, f32 VALU, 16-lane shuffle reduce (first 256 threads)
  if (tid < 256) {
    int m = tid >> 4, j0 = tid & 15;
    float s = 0.f;
    for (int j = j0; j < 100; j += 16)
      s += fmaxf(sG[j * 20 + m], 0.f) * ldf(w4_, j);
    s += __shfl_xor(s, 8); s += __shfl_xor(s, 4);
    s += __shfl_xor(s, 2); s += __shfl_xor(s, 1);
    if (j0 == 0) {
      float v = s + ldf(b4_, 0);
      if constexpr (!F32) ((unsigned short*)out_)[r0 + m] = f2bf(v);
      else                ((float*)out_)[r0 + m] = v;
    }
  }
}

extern "C" void kernel_launch(void* const* d_in, const int* in_sizes, int n_in,
                              void* d_out, int out_size, void* d_ws, size_t ws_size,
                              hipStream_t stream) {
  (void)n_in; (void)out_size;
  // d_in[1..10] (mlp1_* / attn_*) are dead code in the reference — unused.
  const void* state = d_in[0];
  const void* wih = d_in[11]; const void* whh = d_in[12];
  const void* bih = d_in[13]; const void* bhh = d_in[14];
  const void* w1  = d_in[15]; const void* b1  = d_in[16];
  const void* w2  = d_in[17]; const void* b2  = d_in[18];
  const void* w3  = d_in[19]; const void* b3  = d_in[20];
  const void* w4  = d_in[21]; const void* b4  = d_in[22];

  // Host-side dtype selection from the state buffer byte size: one launch.
  const long long F32B  = 8192LL * 64 * 13 * 4;
  const long long BF16B = 8192LL * 64 * 13 * 2;
  long long sz = in_sizes ? (long long)in_sizes[0] : -1;

  if (sz == F32B) {
    value_net_kernel<true><<<dim3(512), dim3(1024), 0, stream>>>(
        state, wih, whh, bih, bhh, w1, b1, w2, b2, w3, b3, w4, b4, d_out,
        (const int*)nullptr);
  } else if (sz == BF16B) {
    value_net_kernel<false><<<dim3(512), dim3(1024), 0, stream>>>(
        state, wih, whh, bih, bhh, w1, b1, w2, b2, w3, b3, w4, b4, d_out,
        (const int*)nullptr);
  } else if (ws_size >= sizeof(int)) {
    // Fallback: on-device detect + both variants (one exits immediately).
    int* flag = (int*)d_ws;
    detect_dtype_kernel<<<dim3(1), dim3(64), 0, stream>>>(
        (const unsigned short*)state, flag);
    value_net_kernel<false><<<dim3(512), dim3(1024), 0, stream>>>(
        state, wih, whh, bih, bhh, w1, b1, w2, b2, w3, b3, w4, b4, d_out, flag);
    value_net_kernel<true><<<dim3(512), dim3(1024), 0, stream>>>(
        state, wih, whh, bih, bhh, w1, b1, w2, b2, w3, b3, w4, b4, d_out, flag);
  } else {
    value_net_kernel<false><<<dim3(512), dim3(1024), 0, stream>>>(
        state, wih, whh, bih, bhh, w1, b1, w2, b2, w3, b3, w4, b4, d_out,
        (const int*)nullptr);
  }
}